// Round 22
// baseline (35.565 us; speedup 1.0000x reference)
//
#include <hip/hip_runtime.h>

// SplineConv as skinny-K GEMM: out[n,oi] = sum_k W[n,k] * CT[k,oi].
// M=32768 points, N=1024 channels, K=64. f16 MFMA 16x16x32, f32 acc.
//
// Round-22 = R21 structure with W-GENERATION FUSED into the main kernel:
//  - prep kernel now ONLY builds Cp (pre-permuted A-fragments, 32 blocks,
//    ~1us) — keeping R18's costly part (serial scalar C-gather) OUT of main.
//  - main kernel phase 1: threads 0-127 compute their block's 128 points'
//    spline weights (verified R13-21 math) and write 8 f16x8 fragment chunks
//    directly into the LDS buffer R21 staged from global. Saves: prep W-pass
//    (~2-3us, it expanded all 32768 points per 256-thread block), 8 MiB of
//    Wp write+read traffic, and the cross-XCD Wp latency.
//  - Loop identical to R21: ds_read_b128 B-frags, 8 MFMAs, wave-private XOR
//    transpose (no barrier), 4 x 256B full-line nt stores, T1 XCD swizzle
//    (confirmed +8%). One __syncthreads total.

#define NPTS   32768
#define DIM    1024
#define MT     (NPTS / 16)        // 2048 point-tiles

typedef _Float16 f16x8 __attribute__((ext_vector_type(8)));
typedef float    f32x4 __attribute__((ext_vector_type(4)));

__device__ __forceinline__ float safe_div(float n, float d) {
    return (d == 0.0f) ? n : (n / d);
}

__device__ __forceinline__ void span_weights(float v, const float* __restrict__ T,
                                             int& k, float& w0, float& w1, float& w2) {
    float t3 = T[3], t4 = T[4], t5 = T[5], t6 = T[6];
    k = 2 + (v >= t3) + (v >= t4) + (v >= t5) + (v >= t6);
    float Tm1 = T[k - 1], T0 = T[k], Tp1 = T[k + 1], Tp2 = T[k + 2];
    float a10 = safe_div(v - Tm1, Tp1 - Tm1);
    float a11 = safe_div(v - T0,  Tp2 - T0);
    float a21 = safe_div(v - T0,  Tp1 - T0);
    w0 = (1.0f - a21) * (1.0f - a10);
    w1 = (1.0f - a21) * a10 + a21 * (1.0f - a11);
    w2 = a21 * a11;
}

// Cp only: C[ch][k] in A-fragment order (row=ch=lane%16, k=(lane/16)*8+st*32+j).
__global__ __launch_bounds__(256) void prep_cp_kernel(
    const float* __restrict__ C,
    _Float16* __restrict__ Cp)
{
    const int id    = blockIdx.x * 256 + threadIdx.x;   // 0 .. 8191
    const int lane  = id & 63;
    const int step  = (id >> 6) & 1;
    const int ctile = id >> 7;
    const int ch    = ctile * 16 + (lane & 15);
    const int g     = lane >> 4;

    f16x8 frag;
#pragma unroll
    for (int j = 0; j < 8; ++j) {
        const int k = step * 32 + g * 8 + j;
        frag[j] = (_Float16)((k < 49) ? C[(size_t)ch * 49 + k] : 0.0f);
    }
    *(f16x8*)(Cp + (size_t)id * 8) = frag;
}

__global__ __launch_bounds__(256, 4) void spline_mfma_kernel(
    const float* __restrict__ xy,
    const float* __restrict__ Tx,
    const float* __restrict__ Ty,
    const _Float16* __restrict__ Cp,
    float* __restrict__ out)
{
    __shared__ _Float16 wlds[8 * 2 * 64 * 8];  // 16 KiB: this block's W frags
    __shared__ float    tbuf[4][1024];         // 16 KiB: wave-private transpose

    const int t    = threadIdx.x;
    const int lane = t & 63;
    const int w    = t >> 6;                   // wave 0..3

    // --- T1 XCD swizzle (confirmed +8%): contiguous output per XCD. ---
    const int bid    = blockIdx.x;
    const int swz    = ((bid & 7) << 7) | (bid >> 3);
    const int chgrp  = swz & 3;                // 256-channel group
    const int pchunk = swz >> 2;               // 8 point-tile chunk (128 points)

    // --- Phase 1: threads 0-127 expand their point's weights into the 8
    // fragment chunks, written straight to LDS (same math as verified prep;
    // record (tile,st,lane) holds point tile*16+(lane&15), k=st*32+(lane>>4)*8+j).
    if (t < 128) {
        const int tl   = t >> 4;               // tile_local 0..7
        const int prow = t & 15;
        const float2 pt2 = ((const float2*)xy)[pchunk * 128 + t];
        int kx, ky;
        float wx0, wx1, wx2, wy0, wy1, wy2;
        span_weights(pt2.x, Tx, kx, wx0, wx1, wx2);
        span_weights(pt2.y, Ty, ky, wy0, wy1, wy2);
        const int off = (kx - 2) * 7 + (ky - 2);
#pragma unroll
        for (int st = 0; st < 2; ++st)
#pragma unroll
            for (int g = 0; g < 4; ++g) {
                f16x8 frag;
#pragma unroll
                for (int j = 0; j < 8; ++j) {
                    const int k   = st * 32 + g * 8 + j;
                    const int rel = k - off;
                    const float va = (rel >= 14) ? wx2 : ((rel >= 7) ? wx1 : wx0);
                    const int   bb = rel - ((rel >= 14) ? 14 : ((rel >= 7) ? 7 : 0));
                    const float vb = (bb == 0) ? wy0 : ((bb == 1) ? wy1 : wy2);
                    const bool valid = (rel >= 0) && (rel <= 16) && (bb >= 0) && (bb <= 2);
                    frag[j] = (_Float16)(valid ? va * vb : 0.0f);
                }
                *(f16x8*)&wlds[(size_t)((tl * 2 + st) * 64 + g * 16 + prow) * 8] = frag;
            }
    }

    // A-fragments from Cp (pre-permuted; 128 KiB, L2-hot; coalesced 16B loads).
    f16x8 af[4][2];
#pragma unroll
    for (int ct = 0; ct < 4; ++ct)
#pragma unroll
        for (int st = 0; st < 2; ++st) {
            const int ctg = chgrp * 16 + w * 4 + ct;
            af[ct][st] = *(const f16x8*)(Cp + ((size_t)(ctg * 2 + st) * 64 + lane) * 8);
        }

    __syncthreads();   // only barrier: W frags visible to all waves

    const int p  = lane & 15;                  // D col = point within tile
    const int h  = lane >> 4;                  // D row group
    const int cb = lane & 15;                  // read-back granule index
    float* const wbuf = &tbuf[w][0];

#pragma unroll
    for (int pt = 0; pt < 8; ++pt) {
        const int ptile = pchunk * 8 + pt;

        // B-fragments from LDS (conflict-free lane*16B ds_read_b128).
        const f16x8 b0 = *(const f16x8*)&wlds[(size_t)((pt * 2 + 0) * 64 + lane) * 8];
        const f16x8 b1 = *(const f16x8*)&wlds[(size_t)((pt * 2 + 1) * 64 + lane) * 8];

        f32x4 acc[4];
#pragma unroll
        for (int ct = 0; ct < 4; ++ct) {
            f32x4 z; z[0] = 0.0f; z[1] = 0.0f; z[2] = 0.0f; z[3] = 0.0f;
            acc[ct] = __builtin_amdgcn_mfma_f32_16x16x32_f16(af[ct][0], b0, z, 0, 0, 0);
        }
#pragma unroll
        for (int ct = 0; ct < 4; ++ct)
            acc[ct] = __builtin_amdgcn_mfma_f32_16x16x32_f16(af[ct][1], b1, acc[ct], 0, 0, 0);

        // --- Wave-private LDS transpose (no barrier), XOR granule swizzle. ---
#pragma unroll
        for (int ct = 0; ct < 4; ++ct) {
            const int g16 = ct * 4 + h;
            const int col = (g16 & 8) | ((g16 ^ p) & 7);
            *(f32x4*)(wbuf + p * 64 + (col << 2)) = acc[ct];
        }

        // --- Read back + store: instr gg covers points gg*4..gg*4+3, each as
        // 16 lanes x 16B = 256B contiguous (2 full 128B lines). ---
#pragma unroll
        for (int gg = 0; gg < 4; ++gg) {
            const int pr  = gg * 4 + h;
            const int col = (cb & 8) | ((cb ^ pr) & 7);
            f32x4 v = *(const f32x4*)(wbuf + pr * 64 + (col << 2));
            float* dst = out + (size_t)(ptile * 16 + pr) * DIM
                             + chgrp * 256 + w * 64 + cb * 4;
            __builtin_nontemporal_store(v, (f32x4*)dst);
        }
    }
}

extern "C" void kernel_launch(void* const* d_in, const int* in_sizes, int n_in,
                              void* d_out, int out_size, void* d_ws, size_t ws_size,
                              hipStream_t stream) {
    const float* xy = (const float*)d_in[0];
    const float* Tx = (const float*)d_in[1];
    const float* Ty = (const float*)d_in[2];
    const float* C  = (const float*)d_in[3];
    float* out = (float*)d_out;

    _Float16* Cp = (_Float16*)d_ws;            // 128 KiB

    prep_cp_kernel<<<32, 256, 0, stream>>>(C, Cp);
    spline_mfma_kernel<<<4 * (MT / 8), 256, 0, stream>>>(xy, Tx, Ty, Cp, out);
}

// Round 23
// 31.575 us; speedup vs baseline: 1.1264x; 1.1264x over previous
//
#include <hip/hip_runtime.h>

// SplineConv as skinny-K GEMM: out[n,oi] = sum_k W[n,k] * CT[k,oi].
// M=32768 points, N=1024 channels, K=64. f16 MFMA 16x16x32, f32 acc.
//
// Round-23 = round-20 (34.0us, best) with ONE change: plain write-back f32x4
// stores instead of nontemporal. R17's plain-store test was PRE-swizzle
// (scattered cross-XCD traffic masked the cache path - regime gating); now
// each XCD writes a contiguous 16MiB slice and the 128MiB output fits the
// 256MiB L3, so write-back lets L2/L3 absorb at fabric rate and drain lazily
// while nt pins the raw HBM path.
//  - T1 XCD swizzle (confirmed +8%), wave-private XOR transpose (no barrier),
//    4 x 256B full-line stores, Wp prefetch-1 - all unchanged from R20.
// prep_kernel identical to R13-R22 (verified, absmax 1.95e-3).

#define NPTS   32768
#define DIM    1024
#define MT     (NPTS / 16)        // 2048 point-tiles
#define WELEM  (MT * 2 * 64 * 8)  // W_perm f16 elements (4 MiB)

typedef _Float16 f16x8 __attribute__((ext_vector_type(8)));
typedef float    f32x4 __attribute__((ext_vector_type(4)));

__device__ __forceinline__ float safe_div(float n, float d) {
    return (d == 0.0f) ? n : (n / d);
}

__device__ __forceinline__ void span_weights(float v, const float* __restrict__ T,
                                             int& k, float& w0, float& w1, float& w2) {
    float t3 = T[3], t4 = T[4], t5 = T[5], t6 = T[6];
    k = 2 + (v >= t3) + (v >= t4) + (v >= t5) + (v >= t6);
    float Tm1 = T[k - 1], T0 = T[k], Tp1 = T[k + 1], Tp2 = T[k + 2];
    float a10 = safe_div(v - Tm1, Tp1 - Tm1);
    float a11 = safe_div(v - T0,  Tp2 - T0);
    float a21 = safe_div(v - T0,  Tp1 - T0);
    w0 = (1.0f - a21) * (1.0f - a10);
    w1 = (1.0f - a21) * a10 + a21 * (1.0f - a11);
    w2 = a21 * a11;
}

__global__ __launch_bounds__(256) void prep_kernel(
    const float* __restrict__ xy,
    const float* __restrict__ Tx,
    const float* __restrict__ Ty,
    const float* __restrict__ C,
    _Float16* __restrict__ Wp,
    _Float16* __restrict__ Cp)
{
    const int b = blockIdx.x;
    const int t = threadIdx.x;
    if (b < MT / 2) {
        // ---- W_perm: one thread per (point-tile, k-step, lane) 16B record ----
        const int id   = b * 256 + t;          // 0 .. 262143
        const int lane = id & 63;
        const int step = (id >> 6) & 1;
        const int tile = id >> 7;
        const int n    = tile * 16 + (lane & 15);   // B col = lane%16
        const int g    = lane >> 4;                  // k-group

        const float2 pt = ((const float2*)xy)[n];
        int kx, ky;
        float wx0, wx1, wx2, wy0, wy1, wy2;
        span_weights(pt.x, Tx, kx, wx0, wx1, wx2);
        span_weights(pt.y, Ty, ky, wy0, wy1, wy2);
        const int off = (kx - 2) * 7 + (ky - 2);

        f16x8 frag;
#pragma unroll
        for (int j = 0; j < 8; ++j) {
            const int k   = step * 32 + g * 8 + j;
            const int rel = k - off;
            const float va = (rel >= 14) ? wx2 : ((rel >= 7) ? wx1 : wx0);
            const int   bb = rel - ((rel >= 14) ? 14 : ((rel >= 7) ? 7 : 0));
            const float vb = (bb == 0) ? wy0 : ((bb == 1) ? wy1 : wy2);
            const bool valid = (rel >= 0) && (rel <= 16) && (bb >= 0) && (bb <= 2);
            frag[j] = (_Float16)(valid ? va * vb : 0.0f);
        }
        *(f16x8*)(Wp + (size_t)id * 8) = frag;
    } else if (b < MT / 2 + 32) {
        // ---- C_perm: C[ch][k] in A-fragment order (row=ch, k-grouped) ----
        const int id    = (b - MT / 2) * 256 + t;   // 0 .. 8191
        const int lane  = id & 63;
        const int step  = (id >> 6) & 1;
        const int ctile = id >> 7;
        const int ch    = ctile * 16 + (lane & 15); // A row = lane%16
        const int g     = lane >> 4;

        f16x8 frag;
#pragma unroll
        for (int j = 0; j < 8; ++j) {
            const int k = step * 32 + g * 8 + j;
            frag[j] = (_Float16)((k < 49) ? C[(size_t)ch * 49 + k] : 0.0f);
        }
        *(f16x8*)(Cp + (size_t)id * 8) = frag;
    }
}

__global__ __launch_bounds__(256, 4) void spline_mfma_kernel(
    const _Float16* __restrict__ Wp,
    const _Float16* __restrict__ Cp,
    float* __restrict__ out)
{
    __shared__ float lds[4 * 1024];            // 4 KiB per wave, private

    const int t    = threadIdx.x;
    const int lane = t & 63;
    const int w    = t >> 6;                   // wave 0..3

    // --- T1 XCD swizzle (confirmed +8%): contiguous output per XCD. ---
    const int bid    = blockIdx.x;
    const int swz    = ((bid & 7) << 7) | (bid >> 3);
    const int chgrp  = swz & 3;                // 256-channel group
    const int pchunk = swz >> 2;               // 8 point-tile chunk (128 points)

    float* const wbuf = lds + w * 1024;        // this wave's region

    // A-fragments: this wave's 4 channel-tiles x 2 k-steps (register-resident;
    // Cp is 128 KiB -> L2-hot for every block).
    f16x8 af[4][2];
#pragma unroll
    for (int ct = 0; ct < 4; ++ct)
#pragma unroll
        for (int st = 0; st < 2; ++st) {
            const int ctg = chgrp * 16 + w * 4 + ct;
            af[ct][st] = *(const f16x8*)(Cp + ((size_t)(ctg * 2 + st) * 64 + lane) * 8);
        }

    const int p  = lane & 15;                  // D col = point within tile
    const int h  = lane >> 4;                  // D row group
    const int cb = lane & 15;                  // read-back granule index

    // Prefetch first tile's B-fragments.
    const int ptile0 = pchunk * 8;
    f16x8 nb0 = *(const f16x8*)(Wp + ((size_t)(ptile0 * 2 + 0) * 64 + lane) * 8);
    f16x8 nb1 = *(const f16x8*)(Wp + ((size_t)(ptile0 * 2 + 1) * 64 + lane) * 8);

#pragma unroll
    for (int pt = 0; pt < 8; ++pt) {
        const int ptile = pchunk * 8 + pt;
        const f16x8 b0 = nb0;
        const f16x8 b1 = nb1;
        if (pt + 1 < 8) {   // issue next tile's loads BEFORE this tile's stores
            nb0 = *(const f16x8*)(Wp + ((size_t)((ptile + 1) * 2 + 0) * 64 + lane) * 8);
            nb1 = *(const f16x8*)(Wp + ((size_t)((ptile + 1) * 2 + 1) * 64 + lane) * 8);
        }

        f32x4 acc[4];
#pragma unroll
        for (int ct = 0; ct < 4; ++ct) {
            f32x4 z; z[0] = 0.0f; z[1] = 0.0f; z[2] = 0.0f; z[3] = 0.0f;
            acc[ct] = __builtin_amdgcn_mfma_f32_16x16x32_f16(af[ct][0], b0, z, 0, 0, 0);
        }
#pragma unroll
        for (int ct = 0; ct < 4; ++ct)
            acc[ct] = __builtin_amdgcn_mfma_f32_16x16x32_f16(af[ct][1], b1, acc[ct], 0, 0, 0);

        // --- Wave-private LDS transpose (no barrier). Write: point p, granule
        // g16 = ct*4+h (channels g16*4..+3 of this wave's 64), XOR-swizzled. ---
#pragma unroll
        for (int ct = 0; ct < 4; ++ct) {
            const int g16 = ct * 4 + h;
            const int col = (g16 & 8) | ((g16 ^ p) & 7);
            *(f32x4*)(wbuf + p * 64 + (col << 2)) = acc[ct];
        }

        // --- Read back + store: instr gg covers points gg*4..gg*4+3, each as
        // 16 lanes x 16B = 256B contiguous (2 full 128B lines). Plain
        // write-back stores: post-swizzle each XCD's slice is contiguous and
        // the output fits L3 -> cache absorbs at fabric rate. ---
#pragma unroll
        for (int gg = 0; gg < 4; ++gg) {
            const int pr  = gg * 4 + h;
            const int col = (cb & 8) | ((cb ^ pr) & 7);
            f32x4 v = *(const f32x4*)(wbuf + pr * 64 + (col << 2));
            float* dst = out + (size_t)(ptile * 16 + pr) * DIM
                             + chgrp * 256 + w * 64 + cb * 4;
            *(f32x4*)dst = v;
        }
    }
}

extern "C" void kernel_launch(void* const* d_in, const int* in_sizes, int n_in,
                              void* d_out, int out_size, void* d_ws, size_t ws_size,
                              hipStream_t stream) {
    const float* xy = (const float*)d_in[0];
    const float* Tx = (const float*)d_in[1];
    const float* Ty = (const float*)d_in[2];
    const float* C  = (const float*)d_in[3];
    float* out = (float*)d_out;

    _Float16* Wp = (_Float16*)d_ws;            // 4 MiB
    _Float16* Cp = Wp + WELEM;                 // 128 KiB

    prep_kernel<<<MT / 2 + 32, 256, 0, stream>>>(xy, Tx, Ty, C, Wp, Cp);
    spline_mfma_kernel<<<4 * (MT / 8), 256, 0, stream>>>(Wp, Cp, out);
}